// Round 17
// baseline (107.906 us; speedup 1.0000x reference)
//
#include <hip/hip_runtime.h>
#include <hip/hip_bf16.h>
#include <math.h>

#define D_MODEL 512
#define NH 8
#define DH 64
#define LA 256
#define LB 256
#define LC 32
#define BATCH 4
#define KC_TOT 8192
#define XN (BATCH * LA * D_MODEL)     // 524288 elems per X tensor
#define WN (D_MODEL * D_MODEL)        // 262144 elems per W tensor

typedef float f32x4 __attribute__((ext_vector_type(4)));
typedef _Float16 f16x8 __attribute__((ext_vector_type(8)));
typedef _Float16 f16x4 __attribute__((ext_vector_type(4)));
typedef unsigned int u32;

#if __has_builtin(__builtin_amdgcn_exp2f)
#define EXP2(x) __builtin_amdgcn_exp2f(x)
#else
#define EXP2(x) exp2f(x)
#endif
// exp(s/sqrt(64)) == exp2(s * 0.125 * log2(e))
#define SCLOG2E 0.18033688011118324f

#define MFMA16F(a, b, c) __builtin_amdgcn_mfma_f32_16x16x32_f16(a, b, c, 0, 0, 0)

static __device__ __forceinline__ u32 pkrtz(float x, float y) {
  auto t = __builtin_amdgcn_cvt_pkrtz(x, y);   // __fp16 ext_vector(2)
  u32 r; __builtin_memcpy(&r, &t, 4);
  return r;
}

// ---------------- cvt: f32 -> f16 for X (Q/K/V inputs) and W matrices ----------------
// dst layout: [Xq | Xk | Xv | Wq | Wk | Wv]
__global__ __launch_bounds__(256) void cvt_kernel(
    const float* __restrict__ X0, const float* __restrict__ X1,
    const float* __restrict__ X2, const float* __restrict__ W0,
    const float* __restrict__ W1, const float* __restrict__ W2,
    _Float16* __restrict__ dst)
{
  const int t = blockIdx.y;
  const float* src;
  size_t n, off;
  switch (t) {
    case 0: src = X0; n = XN; off = 0; break;
    case 1: src = X1; n = XN; off = (size_t)XN; break;
    case 2: src = X2; n = XN; off = 2 * (size_t)XN; break;
    case 3: src = W0; n = WN; off = 3 * (size_t)XN; break;
    case 4: src = W1; n = WN; off = 3 * (size_t)XN + WN; break;
    default: src = W2; n = WN; off = 3 * (size_t)XN + 2 * (size_t)WN; break;
  }
  const size_t i = (size_t)blockIdx.x * 2048 + threadIdx.x * 8;
  if (i >= n) return;
  float4 a = *(const float4*)(src + i);
  float4 b = *(const float4*)(src + i + 4);
  f16x8 r;
  r[0] = (_Float16)a.x; r[1] = (_Float16)a.y; r[2] = (_Float16)a.z; r[3] = (_Float16)a.w;
  r[4] = (_Float16)b.x; r[5] = (_Float16)b.y; r[6] = (_Float16)b.z; r[7] = (_Float16)b.w;
  *(f16x8*)(dst + off + i) = r;
}

// ---------------- projection via MFMA: Y[m,n] = (f16)(sum_k Xh[m,k]*Wh[n,k] + b[n]) ----------------
// Block = 64m x 64n, 4 waves (each 16m x 64n). No LDS, no barriers.
__global__ __launch_bounds__(256) void proj_mfma(
    const _Float16* __restrict__ XWh,
    const float* __restrict__ bq, const float* __restrict__ bk,
    const float* __restrict__ bv,
    _Float16* __restrict__ Qp, _Float16* __restrict__ Kp,
    _Float16* __restrict__ Vp)
{
  const int z = blockIdx.z;
  const _Float16* X = XWh + (size_t)z * XN;
  const _Float16* W = XWh + 3 * (size_t)XN + (size_t)z * WN;
  const float* bias = (z == 0) ? bq : (z == 1) ? bk : bv;
  _Float16* Y = (z == 0) ? Qp : (z == 1) ? Kp : Vp;

  const int tid = threadIdx.x;
  const int lane = tid & 63;
  const int w = tid >> 6;
  const int l16 = lane & 15;
  const int lg = lane >> 4;

  const int n0 = blockIdx.x * 64;
  const int m0 = blockIdx.y * 64;
  const int m = m0 + w * 16 + l16;

  f32x4 acc[4] = {};
  const _Float16* xrow = X + (size_t)m * D_MODEL;
  const _Float16* wbase = W + (size_t)(n0 + l16) * D_MODEL;

#pragma unroll 4
  for (int ks = 0; ks < 16; ++ks) {
    f16x8 bf = *(const f16x8*)(xrow + ks * 32 + lg * 8);
#pragma unroll
    for (int ai = 0; ai < 4; ++ai) {
      f16x8 af = *(const f16x8*)(wbase + (size_t)(ai * 16) * D_MODEL + ks * 32 + lg * 8);
      acc[ai] = MFMA16F(af, bf, acc[ai]);
    }
  }
#pragma unroll
  for (int ai = 0; ai < 4; ++ai) {
    float4 b4 = *(const float4*)&bias[n0 + ai * 16 + lg * 4];
    f16x4 r;
    r[0] = (_Float16)(acc[ai][0] + b4.x);
    r[1] = (_Float16)(acc[ai][1] + b4.y);
    r[2] = (_Float16)(acc[ai][2] + b4.z);
    r[3] = (_Float16)(acc[ai][3] + b4.w);
    *(f16x4*)&Y[(size_t)m * D_MODEL + n0 + ai * 16 + lg * 4] = r;
  }
}

// ---------------- fused attention: one block = one 16-q tile, all 8192 kc ----------------
// 512 threads / 8 waves. Iteration ch covers the contiguous kc strip
// [ch*256, ch*256+256): wave w computes k row ch*8+w (32 kc cols each).
// Pass 1: rowsum of exp(scores) (no stores/barriers). Pass 2: waves publish f16
// P fragments to a block-shared dbuf strip, one barrier, then wave w stores rows
// 2w,2w+1 as 1KB-contiguous wave-instructions (fill-kernel geometry).
// PV via shuffle transpose. Tree reduce (aliases pub) -> out.
#define STG 264   // pub row stride in f16 (528B) — spreads publish banks
__global__ __launch_bounds__(512) void attn_fused(
    const _Float16* __restrict__ Qp, const _Float16* __restrict__ Kp,
    const _Float16* __restrict__ Vp, const float* __restrict__ Ct,
    float* __restrict__ attn, float* __restrict__ out)
{
  __shared__ __align__(16) _Float16 pub[2][16][STG];      // 16.5 KB (aliased for reduce)
  __shared__ __align__(16) _Float16 C_lds[LC][DH + 8];    // 4.6 KB
  __shared__ __align__(16) _Float16 CT_lds[DH][LC + 8];   // 5 KB
  __shared__ float red_lds[8][16];
  __shared__ float inv_lds[16];

  const int tid = threadIdx.x;
  const int lane = tid & 63;
  const int w = tid >> 6;
  const int l16 = lane & 15;
  const int lg = lane >> 4;

  const int tile = blockIdx.x;     // 0..511
  const int bh = tile >> 4;
  const int qt = tile & 15;
  const int b = bh >> 3;
  const int h = bh & 7;

  const _Float16* Kb = Kp + (size_t)b * LB * D_MODEL + h * DH;
  const _Float16* Vb = Vp + (size_t)b * LB * D_MODEL + h * DH;
  const float* Cb = Ct + (size_t)b * LC * D_MODEL + h * DH;

  // ---- stage C, C^T ----
  for (int i = tid; i < LC * DH; i += 512) {
    const int c = i >> 6, d = i & 63;
    _Float16 v = (_Float16)Cb[(size_t)c * D_MODEL + d];
    C_lds[c][d] = v;
    CT_lds[d][c] = v;
  }

  f16x8 qf[2];
  {
    const _Float16* Qb = Qp + (size_t)(b * LA + qt * 16) * D_MODEL + h * DH;
#pragma unroll
    for (int kh = 0; kh < 2; ++kh)
      qf[kh] = *(const f16x8*)(Qb + (size_t)l16 * D_MODEL + kh * 32 + lg * 8);
  }
  __syncthreads();

  // ---- pass 1: rowsum of exp(scores); wave w handles k rows {ch*8+w} ----
  float rs = 0.f;
#pragma unroll 2
  for (int ch = 0; ch < 32; ++ch) {
    const int krow = ch * 8 + w;
    const _Float16* krp = Kb + (size_t)krow * D_MODEL;
    f32x4 s0 = {0.f, 0.f, 0.f, 0.f}, s1 = {0.f, 0.f, 0.f, 0.f};
#pragma unroll
    for (int kh = 0; kh < 2; ++kh) {
      f16x8 kv = *(const f16x8*)(krp + kh * 32 + lg * 8);
      f16x8 c0 = *(const f16x8*)&C_lds[l16][kh * 32 + lg * 8];
      f16x8 c1 = *(const f16x8*)&C_lds[16 + l16][kh * 32 + lg * 8];
      s0 = MFMA16F(kv * c0, qf[kh], s0);
      s1 = MFMA16F(kv * c1, qf[kh], s1);
    }
#pragma unroll
    for (int r = 0; r < 4; ++r)
      rs += EXP2(s0[r] * SCLOG2E) + EXP2(s1[r] * SCLOG2E);
  }
  rs += __shfl_xor(rs, 16);
  rs += __shfl_xor(rs, 32);
  if (lane < 16) red_lds[w][lane] = rs;
  __syncthreads();
  if (tid < 16) {
    float t = 0.f;
#pragma unroll
    for (int ww = 0; ww < 8; ++ww) t += red_lds[ww][tid];
    inv_lds[tid] = 1.f / t;
  }
  __syncthreads();
  const float inv = inv_lds[l16];

  // ---- pass 2: compute -> publish strip -> barrier -> 1KB-contiguous stores + PV ----
  f32x4 oacc[4] = {};
  const int s1i = l16 + ((lg & 1) << 5);   // src lane for B-frag words 0,1
  const int s2i = s1i + 16;                // src lane for B-frag words 2,3
  float* atile = attn + (size_t)(bh * LA + qt * 16) * KC_TOT;
  const int r0 = 2 * w, r1 = 2 * w + 1;    // rows this wave stores

#pragma unroll 1
  for (int ch = 0; ch < 32; ++ch) {
    const int krow = ch * 8 + w;
    const int cur = ch & 1;
    const _Float16* krp = Kb + (size_t)krow * D_MODEL;
    f32x4 s0 = {0.f, 0.f, 0.f, 0.f}, s1 = {0.f, 0.f, 0.f, 0.f};
#pragma unroll
    for (int kh = 0; kh < 2; ++kh) {
      f16x8 kv = *(const f16x8*)(krp + kh * 32 + lg * 8);
      f16x8 c0 = *(const f16x8*)&C_lds[l16][kh * 32 + lg * 8];
      f16x8 c1 = *(const f16x8*)&C_lds[16 + l16][kh * 32 + lg * 8];
      s0 = MFMA16F(kv * c0, qf[kh], s0);
      s1 = MFMA16F(kv * c1, qf[kh], s1);
    }
    f32x4 p0, p1;
#pragma unroll
    for (int r = 0; r < 4; ++r) {
      p0[r] = EXP2(s0[r] * SCLOG2E) * inv;
      p1[r] = EXP2(s1[r] * SCLOG2E) * inv;
    }

    // p (kc at fixed q) -> transposed f16 fragment (q=l16, c=lg*8..+8) via shuffles
    const u32 a0 = pkrtz(p0[0], p0[1]), a1 = pkrtz(p0[2], p0[3]);
    const u32 b0 = pkrtz(p1[0], p1[1]), b1 = pkrtz(p1[2], p1[3]);
    const u32 sa0 = (u32)__shfl((int)a0, s1i), sb0 = (u32)__shfl((int)b0, s1i);
    const u32 sa1 = (u32)__shfl((int)a1, s1i), sb1 = (u32)__shfl((int)b1, s1i);
    const u32 ta0 = (u32)__shfl((int)a0, s2i), tb0 = (u32)__shfl((int)b0, s2i);
    const u32 ta1 = (u32)__shfl((int)a1, s2i), tb1 = (u32)__shfl((int)b1, s2i);
    u32 bw[4];
    bw[0] = (lg < 2) ? sa0 : sb0;
    bw[1] = (lg < 2) ? sa1 : sb1;
    bw[2] = (lg < 2) ? ta0 : tb0;
    bw[3] = (lg < 2) ? ta1 : tb1;
    f16x8 bf; __builtin_memcpy(&bf, bw, 16);

    // publish fragment into the block strip: pub[cur][q=l16][w*32 + lg*8]
    *(f16x8*)&pub[cur][l16][w * 32 + lg * 8] = bf;

    const _Float16* vrow = Vb + (size_t)krow * D_MODEL;
#pragma unroll
    for (int dt = 0; dt < 4; ++dt) {
      const _Float16 vv = vrow[dt * 16 + l16];
      f16x8 ct8 = *(const f16x8*)&CT_lds[dt * 16 + l16][lg * 8];
      oacc[dt] = MFMA16F(ct8 * vv, bf, oacc[dt]);
    }

    __syncthreads();   // strip [ch*256, +256) complete in pub[cur]

    // cooperative store: wave w stores rows 2w, 2w+1 — 1KB contiguous per inst
    {
      f16x4 h0 = *(const f16x4*)&pub[cur][r0][lane * 4];
      f16x4 h1 = *(const f16x4*)&pub[cur][r1][lane * 4];
      f32x4 v0, v1;
#pragma unroll
      for (int r = 0; r < 4; ++r) { v0[r] = (float)h0[r]; v1[r] = (float)h1[r]; }
      *(f32x4*)(atile + (size_t)r0 * KC_TOT + ch * 256 + lane * 4) = v0;
      *(f32x4*)(atile + (size_t)r1 * KC_TOT + ch * 256 + lane * 4) = v1;
    }
  }

  // ---- tree reduce across waves (aliases pub: rounds of 16/8/4 KB) ----
  float* obuf = (float*)&pub[0][0][0];
  __syncthreads();
  if (w >= 4) {
#pragma unroll
    for (int dt = 0; dt < 4; ++dt)
#pragma unroll
      for (int r = 0; r < 4; ++r)
        obuf[(w - 4) * 1024 + l16 * 64 + dt * 16 + lg * 4 + r] = oacc[dt][r];
  }
  __syncthreads();
  if (w < 4) {
#pragma unroll
    for (int dt = 0; dt < 4; ++dt)
#pragma unroll
      for (int r = 0; r < 4; ++r)
        oacc[dt][r] += obuf[w * 1024 + l16 * 64 + dt * 16 + lg * 4 + r];
  }
  __syncthreads();
  if (w >= 2 && w < 4) {
#pragma unroll
    for (int dt = 0; dt < 4; ++dt)
#pragma unroll
      for (int r = 0; r < 4; ++r)
        obuf[(w - 2) * 1024 + l16 * 64 + dt * 16 + lg * 4 + r] = oacc[dt][r];
  }
  __syncthreads();
  if (w < 2) {
#pragma unroll
    for (int dt = 0; dt < 4; ++dt)
#pragma unroll
      for (int r = 0; r < 4; ++r)
        oacc[dt][r] += obuf[w * 1024 + l16 * 64 + dt * 16 + lg * 4 + r];
  }
  __syncthreads();
  if (w == 1) {
#pragma unroll
    for (int dt = 0; dt < 4; ++dt)
#pragma unroll
      for (int r = 0; r < 4; ++r)
        obuf[l16 * 64 + dt * 16 + lg * 4 + r] = oacc[dt][r];
  }
  __syncthreads();
  if (w == 0) {
    const size_t obase = (size_t)(b * LA + qt * 16 + l16) * D_MODEL + h * DH;
#pragma unroll
    for (int dt = 0; dt < 4; ++dt) {
      f32x4 v;
#pragma unroll
      for (int r = 0; r < 4; ++r)
        v[r] = oacc[dt][r] + obuf[l16 * 64 + dt * 16 + lg * 4 + r];
      *(f32x4*)&out[obase + dt * 16 + lg * 4] = v;
    }
  }
}

extern "C" void kernel_launch(void* const* d_in, const int* in_sizes, int n_in,
                              void* d_out, int out_size, void* d_ws, size_t ws_size,
                              hipStream_t stream) {
  const float* Q_in     = (const float*)d_in[0];
  const float* K_in     = (const float*)d_in[1];
  const float* V_in     = (const float*)d_in[2];
  const float* C_tokens = (const float*)d_in[3];
  const float* Wq       = (const float*)d_in[4];
  const float* bq       = (const float*)d_in[5];
  const float* Wk       = (const float*)d_in[6];
  const float* bk       = (const float*)d_in[7];
  const float* Wv       = (const float*)d_in[8];
  const float* bv       = (const float*)d_in[9];

  float* outp  = (float*)d_out;                           // [B,La,512]
  float* attnp = outp + (size_t)BATCH * LA * D_MODEL;     // [B,h,La,8192]

  _Float16* Qp  = (_Float16*)d_ws;                        // [1024,512] f16 x3
  _Float16* Kp  = Qp + (size_t)XN;
  _Float16* Vp  = Kp + (size_t)XN;
  _Float16* XWh = Vp + (size_t)XN;                        // [3*XN + 3*WN] f16

  cvt_kernel<<<dim3(256, 6), 256, 0, stream>>>(Q_in, K_in, V_in, Wq, Wk, Wv, XWh);
  proj_mfma<<<dim3(8, 16, 3), 256, 0, stream>>>(XWh, bq, bk, bv, Qp, Kp, Vp);
  attn_fused<<<512, 512, 0, stream>>>(Qp, Kp, Vp, C_tokens, attnp, outp);
}

// Round 18
// 92.353 us; speedup vs baseline: 1.1684x; 1.1684x over previous
//
#include <hip/hip_runtime.h>
#include <hip/hip_bf16.h>
#include <math.h>

#define D_MODEL 512
#define NH 8
#define DH 64
#define LA 256
#define LB 256
#define LC 32
#define BATCH 4
#define KC_TOT 8192
#define XN (BATCH * LA * D_MODEL)     // 524288 elems per X tensor
#define WN (D_MODEL * D_MODEL)        // 262144 elems per W tensor

typedef float f32x4 __attribute__((ext_vector_type(4)));
typedef _Float16 f16x8 __attribute__((ext_vector_type(8)));
typedef _Float16 f16x4 __attribute__((ext_vector_type(4)));
typedef unsigned int u32;

#if __has_builtin(__builtin_amdgcn_exp2f)
#define EXP2(x) __builtin_amdgcn_exp2f(x)
#else
#define EXP2(x) exp2f(x)
#endif
// exp(s/sqrt(64)) == exp2(s * 0.125 * log2(e))
#define SCLOG2E 0.18033688011118324f

#define MFMA16F(a, b, c) __builtin_amdgcn_mfma_f32_16x16x32_f16(a, b, c, 0, 0, 0)

static __device__ __forceinline__ u32 pkrtz(float x, float y) {
  auto t = __builtin_amdgcn_cvt_pkrtz(x, y);   // __fp16 ext_vector(2)
  u32 r; __builtin_memcpy(&r, &t, 4);
  return r;
}

// ---------------- cvt: f32 -> f16 for X (Q/K/V inputs) and W matrices ----------------
// dst layout: [Xq | Xk | Xv | Wq | Wk | Wv]
__global__ __launch_bounds__(256) void cvt_kernel(
    const float* __restrict__ X0, const float* __restrict__ X1,
    const float* __restrict__ X2, const float* __restrict__ W0,
    const float* __restrict__ W1, const float* __restrict__ W2,
    _Float16* __restrict__ dst)
{
  const int t = blockIdx.y;
  const float* src;
  size_t n, off;
  switch (t) {
    case 0: src = X0; n = XN; off = 0; break;
    case 1: src = X1; n = XN; off = (size_t)XN; break;
    case 2: src = X2; n = XN; off = 2 * (size_t)XN; break;
    case 3: src = W0; n = WN; off = 3 * (size_t)XN; break;
    case 4: src = W1; n = WN; off = 3 * (size_t)XN + WN; break;
    default: src = W2; n = WN; off = 3 * (size_t)XN + 2 * (size_t)WN; break;
  }
  const size_t i = (size_t)blockIdx.x * 2048 + threadIdx.x * 8;
  if (i >= n) return;
  float4 a = *(const float4*)(src + i);
  float4 b = *(const float4*)(src + i + 4);
  f16x8 r;
  r[0] = (_Float16)a.x; r[1] = (_Float16)a.y; r[2] = (_Float16)a.z; r[3] = (_Float16)a.w;
  r[4] = (_Float16)b.x; r[5] = (_Float16)b.y; r[6] = (_Float16)b.z; r[7] = (_Float16)b.w;
  *(f16x8*)(dst + off + i) = r;
}

// ---------------- projection via MFMA: Y[m,n] = (f16)(sum_k Xh[m,k]*Wh[n,k] + b[n]) ----------------
// Block = 64m x 64n, 4 waves (each 16m x 64n). No LDS, no barriers.
__global__ __launch_bounds__(256) void proj_mfma(
    const _Float16* __restrict__ XWh,
    const float* __restrict__ bq, const float* __restrict__ bk,
    const float* __restrict__ bv,
    _Float16* __restrict__ Qp, _Float16* __restrict__ Kp,
    _Float16* __restrict__ Vp)
{
  const int z = blockIdx.z;
  const _Float16* X = XWh + (size_t)z * XN;
  const _Float16* W = XWh + 3 * (size_t)XN + (size_t)z * WN;
  const float* bias = (z == 0) ? bq : (z == 1) ? bk : bv;
  _Float16* Y = (z == 0) ? Qp : (z == 1) ? Kp : Vp;

  const int tid = threadIdx.x;
  const int lane = tid & 63;
  const int w = tid >> 6;
  const int l16 = lane & 15;
  const int lg = lane >> 4;

  const int n0 = blockIdx.x * 64;
  const int m0 = blockIdx.y * 64;
  const int m = m0 + w * 16 + l16;

  f32x4 acc[4] = {};
  const _Float16* xrow = X + (size_t)m * D_MODEL;
  const _Float16* wbase = W + (size_t)(n0 + l16) * D_MODEL;

#pragma unroll 4
  for (int ks = 0; ks < 16; ++ks) {
    f16x8 bf = *(const f16x8*)(xrow + ks * 32 + lg * 8);
#pragma unroll
    for (int ai = 0; ai < 4; ++ai) {
      f16x8 af = *(const f16x8*)(wbase + (size_t)(ai * 16) * D_MODEL + ks * 32 + lg * 8);
      acc[ai] = MFMA16F(af, bf, acc[ai]);
    }
  }
#pragma unroll
  for (int ai = 0; ai < 4; ++ai) {
    float4 b4 = *(const float4*)&bias[n0 + ai * 16 + lg * 4];
    f16x4 r;
    r[0] = (_Float16)(acc[ai][0] + b4.x);
    r[1] = (_Float16)(acc[ai][1] + b4.y);
    r[2] = (_Float16)(acc[ai][2] + b4.z);
    r[3] = (_Float16)(acc[ai][3] + b4.w);
    *(f16x4*)&Y[(size_t)m * D_MODEL + n0 + ai * 16 + lg * 4] = r;
  }
}

// ---------------- fused attention: one block = one 16-q tile, all 8192 kc ----------------
// 512 threads / 8 waves; wave w owns kc slice [w*1024, +1024) = k rows [w*32, +32).
// Pass 2 decouples attn stores from compute: K(ch+1)/V(ch+1) are register-
// prefetched at the TOP of iteration ch, before store(ch-1) is issued, so the
// in-order vmcnt wait for the next K never forces the older stores to drain.
// Transposed f16 P fragment staged in wave-private dbuf LDS, stored cooperatively
// next ch. PV via shuffle transpose. No barriers in hot loops. Tree reduce -> out.
#define STG 40   // stage row stride (f16 elems); 80B
__global__ __launch_bounds__(512) void attn_fused(
    const _Float16* __restrict__ Qp, const _Float16* __restrict__ Kp,
    const _Float16* __restrict__ Vp, const float* __restrict__ Ct,
    float* __restrict__ attn, float* __restrict__ out)
{
  __shared__ __align__(16) _Float16 stage[8][2][16][STG]; // 20 KB (aliased for reduce)
  __shared__ __align__(16) _Float16 C_lds[LC][DH + 8];    // 4.6 KB
  __shared__ __align__(16) _Float16 CT_lds[DH][LC + 8];   // 5 KB
  __shared__ float red_lds[8][16];
  __shared__ float inv_lds[16];

  const int tid = threadIdx.x;
  const int lane = tid & 63;
  const int w = tid >> 6;
  const int l16 = lane & 15;
  const int lg = lane >> 4;

  const int tile = blockIdx.x;     // 0..511
  const int bh = tile >> 4;
  const int qt = tile & 15;
  const int b = bh >> 3;
  const int h = bh & 7;

  const _Float16* Kb = Kp + (size_t)b * LB * D_MODEL + h * DH;
  const _Float16* Vb = Vp + (size_t)b * LB * D_MODEL + h * DH;
  const float* Cb = Ct + (size_t)b * LC * D_MODEL + h * DH;

  // ---- stage C, C^T ----
  for (int i = tid; i < LC * DH; i += 512) {
    const int c = i >> 6, d = i & 63;
    _Float16 v = (_Float16)Cb[(size_t)c * D_MODEL + d];
    C_lds[c][d] = v;
    CT_lds[d][c] = v;
  }

  f16x8 qf[2];
  {
    const _Float16* Qb = Qp + (size_t)(b * LA + qt * 16) * D_MODEL + h * DH;
#pragma unroll
    for (int kh = 0; kh < 2; ++kh)
      qf[kh] = *(const f16x8*)(Qb + (size_t)l16 * D_MODEL + kh * 32 + lg * 8);
  }
  __syncthreads();

  // ---- pass 1: rowsum of exp(scores) over this wave's 32 k rows ----
  float rs = 0.f;
#pragma unroll 2
  for (int ch = 0; ch < 32; ++ch) {
    const int krow = w * 32 + ch;
    const _Float16* krp = Kb + (size_t)krow * D_MODEL;
    f32x4 s0 = {0.f, 0.f, 0.f, 0.f}, s1 = {0.f, 0.f, 0.f, 0.f};
#pragma unroll
    for (int kh = 0; kh < 2; ++kh) {
      f16x8 kv = *(const f16x8*)(krp + kh * 32 + lg * 8);
      f16x8 c0 = *(const f16x8*)&C_lds[l16][kh * 32 + lg * 8];
      f16x8 c1 = *(const f16x8*)&C_lds[16 + l16][kh * 32 + lg * 8];
      s0 = MFMA16F(kv * c0, qf[kh], s0);
      s1 = MFMA16F(kv * c1, qf[kh], s1);
    }
#pragma unroll
    for (int r = 0; r < 4; ++r)
      rs += EXP2(s0[r] * SCLOG2E) + EXP2(s1[r] * SCLOG2E);
  }
  rs += __shfl_xor(rs, 16);
  rs += __shfl_xor(rs, 32);
  if (lane < 16) red_lds[w][lane] = rs;
  __syncthreads();
  if (tid < 16) {
    float t = 0.f;
#pragma unroll
    for (int ww = 0; ww < 8; ++ww) t += red_lds[ww][tid];
    inv_lds[tid] = 1.f / t;
  }
  __syncthreads();
  const float inv = inv_lds[l16];

  // ---- pass 2: prefetch K/V(ch+1) -> compute(ch) -> stage -> PV -> store(ch-1) ----
  f32x4 oacc[4] = {};
  const int s1i = l16 + ((lg & 1) << 5);   // src lane for B-frag words 0,1
  const int s2i = s1i + 16;                // src lane for B-frag words 2,3
  const int strow = lane >> 3;             // store row (and +8)
  const int stcol = (lane & 7) * 4;        // store col
  float* abase = attn + (size_t)(bh * LA + qt * 16) * KC_TOT + w * 1024;

  // preload ch = 0
  f16x8 kvA, kvB;
  f16x4 vvc;
  {
    const _Float16* krp0 = Kb + (size_t)(w * 32) * D_MODEL;
    kvA = *(const f16x8*)(krp0 + lg * 8);
    kvB = *(const f16x8*)(krp0 + 32 + lg * 8);
    const _Float16* vr0 = Vb + (size_t)(w * 32) * D_MODEL;
#pragma unroll
    for (int dt = 0; dt < 4; ++dt) vvc[dt] = vr0[dt * 16 + l16];
  }

#pragma unroll 2
  for (int ch = 0; ch < 32; ++ch) {
    const int krow = w * 32 + ch;
    const int cur = ch & 1;

    // ---- prefetch next iteration's K/V FIRST (before any stores this iter) ----
    const int krow_n = krow + ((ch < 31) ? 1 : 0);
    const _Float16* krp_n = Kb + (size_t)krow_n * D_MODEL;
    f16x8 kvA_n = *(const f16x8*)(krp_n + lg * 8);
    f16x8 kvB_n = *(const f16x8*)(krp_n + 32 + lg * 8);
    const _Float16* vr_n = Vb + (size_t)krow_n * D_MODEL;
    f16x4 vv_n;
#pragma unroll
    for (int dt = 0; dt < 4; ++dt) vv_n[dt] = vr_n[dt * 16 + l16];

    // ---- scores from preloaded K ----
    f32x4 s0 = {0.f, 0.f, 0.f, 0.f}, s1 = {0.f, 0.f, 0.f, 0.f};
    {
      f16x8 c0 = *(const f16x8*)&C_lds[l16][lg * 8];
      f16x8 c1 = *(const f16x8*)&C_lds[16 + l16][lg * 8];
      s0 = MFMA16F(kvA * c0, qf[0], s0);
      s1 = MFMA16F(kvA * c1, qf[0], s1);
      f16x8 c2 = *(const f16x8*)&C_lds[l16][32 + lg * 8];
      f16x8 c3 = *(const f16x8*)&C_lds[16 + l16][32 + lg * 8];
      s0 = MFMA16F(kvB * c2, qf[1], s0);
      s1 = MFMA16F(kvB * c3, qf[1], s1);
    }
    f32x4 p0, p1;
#pragma unroll
    for (int r = 0; r < 4; ++r) {
      p0[r] = EXP2(s0[r] * SCLOG2E) * inv;
      p1[r] = EXP2(s1[r] * SCLOG2E) * inv;
    }

    // p (kc at fixed q) -> transposed f16 fragment (q=l16, c=lg*8..+8) via shuffles
    const u32 a0 = pkrtz(p0[0], p0[1]), a1 = pkrtz(p0[2], p0[3]);
    const u32 b0 = pkrtz(p1[0], p1[1]), b1 = pkrtz(p1[2], p1[3]);
    const u32 sa0 = (u32)__shfl((int)a0, s1i), sb0 = (u32)__shfl((int)b0, s1i);
    const u32 sa1 = (u32)__shfl((int)a1, s1i), sb1 = (u32)__shfl((int)b1, s1i);
    const u32 ta0 = (u32)__shfl((int)a0, s2i), tb0 = (u32)__shfl((int)b0, s2i);
    const u32 ta1 = (u32)__shfl((int)a1, s2i), tb1 = (u32)__shfl((int)b1, s2i);
    u32 bw[4];
    bw[0] = (lg < 2) ? sa0 : sb0;
    bw[1] = (lg < 2) ? sa1 : sb1;
    bw[2] = (lg < 2) ? ta0 : tb0;
    bw[3] = (lg < 2) ? ta1 : tb1;
    f16x8 bf; __builtin_memcpy(&bf, bw, 16);

    // stage transposed fragment (wave-private dbuf): one f16x8 write per lane
    *(f16x8*)&stage[w][cur][l16][lg * 8] = bf;

    // ---- PV from preloaded V ----
#pragma unroll
    for (int dt = 0; dt < 4; ++dt) {
      f16x8 ct8 = *(const f16x8*)&CT_lds[dt * 16 + l16][lg * 8];
      oacc[dt] = MFMA16F(ct8 * vvc[dt], bf, oacc[dt]);
    }

    // ---- cooperative store of PREVIOUS ch (issued after this iter's prefetch) ----
    if (ch > 0) {
      const int pc = ch - 1;
      const int pb = pc & 1;
      f16x4 h0 = *(const f16x4*)&stage[w][pb][strow][stcol];
      f16x4 h1 = *(const f16x4*)&stage[w][pb][strow + 8][stcol];
      f32x4 v0, v1;
#pragma unroll
      for (int r = 0; r < 4; ++r) { v0[r] = (float)h0[r]; v1[r] = (float)h1[r]; }
      *(f32x4*)(abase + (size_t)strow * KC_TOT + pc * 32 + stcol) = v0;
      *(f32x4*)(abase + (size_t)(strow + 8) * KC_TOT + pc * 32 + stcol) = v1;
    }

    kvA = kvA_n; kvB = kvB_n; vvc = vv_n;
  }
  // drain last ch
  {
    f16x4 h0 = *(const f16x4*)&stage[w][1][strow][stcol];
    f16x4 h1 = *(const f16x4*)&stage[w][1][strow + 8][stcol];
    f32x4 v0, v1;
#pragma unroll
    for (int r = 0; r < 4; ++r) { v0[r] = (float)h0[r]; v1[r] = (float)h1[r]; }
    *(f32x4*)(abase + (size_t)strow * KC_TOT + 31 * 32 + stcol) = v0;
    *(f32x4*)(abase + (size_t)(strow + 8) * KC_TOT + 31 * 32 + stcol) = v1;
  }

  // ---- tree reduce across waves (aliases stage: rounds of 16/8/4 KB) ----
  float* obuf = (float*)&stage[0][0][0][0];
  __syncthreads();
  if (w >= 4) {
#pragma unroll
    for (int dt = 0; dt < 4; ++dt)
#pragma unroll
      for (int r = 0; r < 4; ++r)
        obuf[(w - 4) * 1024 + l16 * 64 + dt * 16 + lg * 4 + r] = oacc[dt][r];
  }
  __syncthreads();
  if (w < 4) {
#pragma unroll
    for (int dt = 0; dt < 4; ++dt)
#pragma unroll
      for (int r = 0; r < 4; ++r)
        oacc[dt][r] += obuf[w * 1024 + l16 * 64 + dt * 16 + lg * 4 + r];
  }
  __syncthreads();
  if (w >= 2 && w < 4) {
#pragma unroll
    for (int dt = 0; dt < 4; ++dt)
#pragma unroll
      for (int r = 0; r < 4; ++r)
        obuf[(w - 2) * 1024 + l16 * 64 + dt * 16 + lg * 4 + r] = oacc[dt][r];
  }
  __syncthreads();
  if (w < 2) {
#pragma unroll
    for (int dt = 0; dt < 4; ++dt)
#pragma unroll
      for (int r = 0; r < 4; ++r)
        oacc[dt][r] += obuf[w * 1024 + l16 * 64 + dt * 16 + lg * 4 + r];
  }
  __syncthreads();
  if (w == 1) {
#pragma unroll
    for (int dt = 0; dt < 4; ++dt)
#pragma unroll
      for (int r = 0; r < 4; ++r)
        obuf[l16 * 64 + dt * 16 + lg * 4 + r] = oacc[dt][r];
  }
  __syncthreads();
  if (w == 0) {
    const size_t obase = (size_t)(b * LA + qt * 16 + l16) * D_MODEL + h * DH;
#pragma unroll
    for (int dt = 0; dt < 4; ++dt) {
      f32x4 v;
#pragma unroll
      for (int r = 0; r < 4; ++r)
        v[r] = oacc[dt][r] + obuf[l16 * 64 + dt * 16 + lg * 4 + r];
      *(f32x4*)&out[obase + dt * 16 + lg * 4] = v;
    }
  }
}

extern "C" void kernel_launch(void* const* d_in, const int* in_sizes, int n_in,
                              void* d_out, int out_size, void* d_ws, size_t ws_size,
                              hipStream_t stream) {
  const float* Q_in     = (const float*)d_in[0];
  const float* K_in     = (const float*)d_in[1];
  const float* V_in     = (const float*)d_in[2];
  const float* C_tokens = (const float*)d_in[3];
  const float* Wq       = (const float*)d_in[4];
  const float* bq       = (const float*)d_in[5];
  const float* Wk       = (const float*)d_in[6];
  const float* bk       = (const float*)d_in[7];
  const float* Wv       = (const float*)d_in[8];
  const float* bv       = (const float*)d_in[9];

  float* outp  = (float*)d_out;                           // [B,La,512]
  float* attnp = outp + (size_t)BATCH * LA * D_MODEL;     // [B,h,La,8192]

  _Float16* Qp  = (_Float16*)d_ws;                        // [1024,512] f16 x3
  _Float16* Kp  = Qp + (size_t)XN;
  _Float16* Vp  = Kp + (size_t)XN;
  _Float16* XWh = Vp + (size_t)XN;                        // [3*XN + 3*WN] f16

  cvt_kernel<<<dim3(256, 6), 256, 0, stream>>>(Q_in, K_in, V_in, Wq, Wk, Wv, XWh);
  proj_mfma<<<dim3(8, 16, 3), 256, 0, stream>>>(XWh, bq, bk, bv, Qp, Kp, Vp);
  attn_fused<<<512, 512, 0, stream>>>(Qp, Kp, Vp, C_tokens, attnp, outp);
}